// Round 5
// baseline (940.198 us; speedup 1.0000x reference)
//
#include <hip/hip_runtime.h>
#include <hip/hip_bf16.h>
#include <math.h>

// Problem constants (fixed by the reference setup_inputs)
#define BB 32
#define PP 24564
#define OO 16
#define CC 81
#define BP (BB * PP)
#define CHUNK 1024        // priors per k_match_a block
#define TILES (BP / 16)   // 49128 16-row tiles, exact
#define NWAVES 4096       // k_ce: 1024 blocks x 4 waves, persistent

typedef unsigned long long ull;

__device__ __forceinline__ float sl1(float x) {
    float ax = fabsf(x);
    return ax < 1.0f ? 0.5f * ax * ax : ax - 0.5f;
}

// ---------------------------------------------------------------------------
// K1a: matching. Writes per-prior packed code = tgt | (best_truth_idx << 8)
// and per-truth best-prior via packed-key atomicMax (max iou, tie: smallest p)
// ---------------------------------------------------------------------------
__global__ __launch_bounds__(256) void k_match_a(
        const float* __restrict__ priors, const float* __restrict__ truths,
        const int* __restrict__ labels, int* __restrict__ codes,
        ull* __restrict__ best_prior /* [BB][OO], pre-zeroed */) {
    const int b = blockIdx.y;
    const int p0 = blockIdx.x * CHUNK;
    const int tid = threadIdx.x;
    __shared__ float tr[OO][4];
    __shared__ float tarea[OO];
    __shared__ int slab[OO];
    __shared__ ull red[OO];
    if (tid < OO * 4) ((float*)tr)[tid] = truths[b * OO * 4 + tid];
    if (tid < OO) { red[tid] = 0ull; slab[tid] = labels[b * OO + tid]; }
    __syncthreads();
    if (tid < OO) tarea[tid] = (tr[tid][2] - tr[tid][0]) * (tr[tid][3] - tr[tid][1]);
    __syncthreads();

    float bpv[OO];
    int bpi[OO];
#pragma unroll
    for (int o = 0; o < OO; o++) { bpv[o] = -1.0f; bpi[o] = -1; }

    const int pend = (p0 + CHUNK < PP) ? p0 + CHUNK : PP;
    for (int p = p0 + tid; p < pend; p += 256) {
        const float4 pr = ((const float4*)priors)[p];
        const float x1 = pr.x - pr.z * 0.5f, y1 = pr.y - pr.w * 0.5f;
        const float x2 = pr.x + pr.z * 0.5f, y2 = pr.y + pr.w * 0.5f;
        const float parea = (x2 - x1) * (y2 - y1);
        float best = -1.0f;
        int bidx = 0;
#pragma unroll
        for (int o = 0; o < OO; o++) {
            const float lx = fmaxf(tr[o][0], x1), ly = fmaxf(tr[o][1], y1);
            const float rx = fminf(tr[o][2], x2), ry = fminf(tr[o][3], y2);
            const float iw = fmaxf(rx - lx, 0.0f), ih = fmaxf(ry - ly, 0.0f);
            const float inter = iw * ih;
            const float iou = inter / (tarea[o] + parea - inter);
            if (iou > best) { best = iou; bidx = o; }          // first-max over o
            if (iou > bpv[o]) { bpv[o] = iou; bpi[o] = p; }    // p ascending per thread
        }
        const int tgt = (best < 0.5f) ? 0 : slab[bidx];
        codes[(size_t)b * PP + p] = tgt | (bidx << 8);
    }

#pragma unroll
    for (int o = 0; o < OO; o++) {
        if (bpi[o] >= 0) {
            const ull key = ((ull)__float_as_uint(bpv[o]) << 32) |
                            (ull)(0xFFFFFFFFu - (unsigned)bpi[o]);
            atomicMax(&red[o], key);
        }
    }
    __syncthreads();
    if (tid < OO && red[tid] != 0ull)
        atomicMax(&best_prior[b * OO + tid], red[tid]);
}

// K1b: sequential (numpy last-writer-wins) override, one thread per batch.
__global__ void k_match_b(const ull* __restrict__ best_prior,
                          const int* __restrict__ labels,
                          int* __restrict__ codes) {
    const int b = threadIdx.x;
    if (b >= BB) return;
    for (int o = 0; o < OO; o++) {
        const unsigned p = 0xFFFFFFFFu - (unsigned)(best_prior[b * OO + o] & 0xFFFFFFFFull);
        codes[(size_t)b * PP + p] = labels[b * OO + o] | (o << 8);  // iou=2.0 >= 0.5
    }
}

// ---------------------------------------------------------------------------
// K2: persistent pipelined CE. 1024 blocks (4/CU) x 4 waves; each wave
// grid-strides over 16-row tiles with depth-2 register prefetch: while tile t
// is computed from LDS, tiles t+1/t+2 global loads are in flight. No
// __syncthreads; only lgkmcnt(0) (LDS-only) waits -- vmem stays outstanding.
// acc: [0]=loss_l [1]=pos_ce_obj [2]=pos_ce_c [3]=neg_obj [4]=neg_c
// ---------------------------------------------------------------------------
__global__ __launch_bounds__(256, 4) void k_ce(
        const float* __restrict__ conf, const float* __restrict__ obj,
        const float* __restrict__ loc, const float* __restrict__ priors,
        const float* __restrict__ truths, const int* __restrict__ codes,
        float* __restrict__ mining_obj, float* __restrict__ mining_c,
        int* __restrict__ num_pos, float* __restrict__ acc) {
    const int w = threadIdx.x >> 6;
    const int L = threadIdx.x & 63;
    const int gw = blockIdx.x * 4 + w;          // 0..NWAVES-1
    __shared__ float sconf[4][16 * CC];         // 5184 B per wave region
    float* lds = sconf[w];
    float4* lds4 = (float4*)lds;

    float4 fA[5], fB[5], ftA = {0,0,0,0}, ftB = {0,0,0,0};
    int codeA = 0, codeB = 0;
    float2 oA = {0.f, 0.f}, oB = {0.f, 0.f};

    auto LOADT = [&](int t, float4 (&f)[5], float4& ft, int& code, float2& o2) {
        const int rb = t * 16;
        const float4* s4 = (const float4*)conf + (size_t)rb * CC / 4;  // 1296 floats
#pragma unroll
        for (int it = 0; it < 5; ++it) f[it] = s4[L + 64 * it];
        if (L < 4) ft = s4[320 + L];
        if (L < 16) { code = codes[rb + L]; o2 = ((const float2*)obj)[rb + L]; }
    };

    auto STORE_LDS = [&](float4 (&f)[5], float4& ft) {
#pragma unroll
        for (int it = 0; it < 5; ++it) lds4[L + 64 * it] = f[it];
        if (L < 4) lds4[320 + L] = ft;
    };

    auto COMPUTE = [&](int t, int code, float2 o2) {
        const int rb = t * 16;
        const int r = L >> 2, part = L & 3;
        const float* rowp = lds + r * CC + part * 20;
        float rv[21];
#pragma unroll
        for (int c = 0; c < 20; ++c) rv[c] = rowp[c];
        rv[20] = (part == 3) ? rowp[20] : -INFINITY;   // 20,20,20,21 split of 81
        float m = rv[0];
#pragma unroll
        for (int c = 1; c < 21; ++c) m = fmaxf(m, rv[c]);
        m = fmaxf(m, __shfl_xor(m, 1));
        m = fmaxf(m, __shfl_xor(m, 2));
        float s = 0.0f;
#pragma unroll
        for (int c = 0; c < 21; ++c) s += __expf(rv[c] - m);  // exp(-inf)=0 pad
        s += __shfl_xor(s, 1);
        s += __shfl_xor(s, 2);
        const float lse = m + __logf(s);                // valid in all 4 quad lanes
        const float lse_row = __shfl(lse, (L & 15) * 4);
        if (L < 16) {
            const int row = rb + L;
            const int b = row / PP;
            const int tgt = code & 255;
            const int ti = code >> 8;
            const float ce_c = lse_row - lds[L * CC + tgt];
            const float mo = fmaxf(o2.x, o2.y);
            const float lse_o = mo + __logf(__expf(o2.x - mo) + __expf(o2.y - mo));
            const bool pos = tgt > 0;
            const float ce_o = lse_o - (pos ? o2.y : o2.x);
            mining_c[row]   = pos ? 0.0f : ce_c;
            mining_obj[row] = pos ? 0.0f : ce_o;
            if (pos) {
                const int p = row - b * PP;
                atomicAdd(&num_pos[b], 1);
                atomicAdd(&acc[1], ce_o);
                atomicAdd(&acc[2], ce_c);
                const float4 pr = ((const float4*)priors)[p];
                const float4 tt = ((const float4*)truths)[b * OO + ti];
                const float gcx = ((tt.x + tt.z) * 0.5f - pr.x) / (0.1f * pr.z);
                const float gcy = ((tt.y + tt.w) * 0.5f - pr.y) / (0.1f * pr.w);
                const float gw2 = logf((tt.z - tt.x) / pr.z) / 0.2f;
                const float gh2 = logf((tt.w - tt.y) / pr.w) / 0.2f;
                const float4 ld = ((const float4*)loc)[row];
                const float l = sl1(ld.x - gcx) + sl1(ld.y - gcy) +
                                sl1(ld.z - gw2) + sl1(ld.w - gh2);
                atomicAdd(&acc[0], l);
            }
        }
    };

    // depth-2 pipeline over this wave's tiles: gw, gw+4096, gw+8192, ...
    if (gw < TILES) LOADT(gw, fA, ftA, codeA, oA);
    if (gw + NWAVES < TILES) LOADT(gw + NWAVES, fB, ftB, codeB, oB);

    for (int t = gw; t < TILES; t += 2 * NWAVES) {
        {
            const int code = codeA; const float2 o2 = oA;
            STORE_LDS(fA, ftA);                       // waits only A's vmem
            if (t + 2 * NWAVES < TILES)
                LOADT(t + 2 * NWAVES, fA, ftA, codeA, oA);  // issue next A
            asm volatile("s_waitcnt lgkmcnt(0)" ::: "memory");  // LDS only
            __builtin_amdgcn_wave_barrier();
            COMPUTE(t, code, o2);
        }
        const int tb = t + NWAVES;
        if (tb < TILES) {
            const int code = codeB; const float2 o2 = oB;
            STORE_LDS(fB, ftB);
            if (tb + 2 * NWAVES < TILES)
                LOADT(tb + 2 * NWAVES, fB, ftB, codeB, oB);
            asm volatile("s_waitcnt lgkmcnt(0)" ::: "memory");
            __builtin_amdgcn_wave_barrier();
            COMPUTE(tb, code, o2);
        }
        __builtin_amdgcn_wave_barrier();
    }
}

// ---------------------------------------------------------------------------
// K3: top-k sum via atomic-free bitwise binary search for the k-th largest.
// 64 blocks ({obj,c} x 32 batches) x 1024 threads; each thread holds 24
// values in registers (pad 0.0 is neutral). 31 iterations of compare-count +
// block reduction narrow the exact bit pattern P of the k-th largest; then
// sum = sum(v > P) + (k - cnt_gt) * P.
// ---------------------------------------------------------------------------
__global__ __launch_bounds__(1024) void k_select(
        const float* __restrict__ mining /* [2][B][P] */,
        const int* __restrict__ num_pos, float* __restrict__ acc,
        int* __restrict__ n1_acc) {
    const int arr = blockIdx.x >> 5;  // 0 = obj, 1 = c
    const int b = blockIdx.x & 31;
    const int tid = threadIdx.x;
    const int lane = tid & 63, wid = tid >> 6;
    const float* x = mining + ((size_t)arr * BB + b) * PP;
    const int np = num_pos[b];
    const long long k64 = 3LL * np;
    const int k = (int)(k64 < (long long)(PP - 1) ? k64 : (long long)(PP - 1));
    if (tid == 0 && arr == 0) atomicAdd(n1_acc, k);
    if (k <= 0) return;  // uniform across block

    unsigned v[24];
#pragma unroll
    for (int j = 0; j < 24; ++j) {
        const int i = tid + j * 1024;
        v[j] = (i < PP) ? __float_as_uint(x[i]) : 0u;
    }

    __shared__ unsigned wred[2][16];
    __shared__ unsigned sbc[2];
    unsigned P = 0;
    for (int bit = 30; bit >= 0; --bit) {
        const unsigned qs = (P >> bit) | 1u;     // (P | 1<<bit) >> bit
        unsigned c = 0;
#pragma unroll
        for (int j = 0; j < 24; ++j) c += ((v[j] >> bit) >= qs) ? 1u : 0u;
#pragma unroll
        for (int off = 32; off; off >>= 1) c += __shfl_xor(c, off);
        const int par = bit & 1;
        if (lane == 0) wred[par][wid] = c;
        __syncthreads();
        if (tid == 0) {
            unsigned tot = 0;
            for (int i = 0; i < 16; ++i) tot += wred[par][i];
            sbc[par] = tot;
        }
        __syncthreads();
        if (sbc[par] >= (unsigned)k) P |= (1u << bit);
    }

    float sum = 0.0f;
    unsigned cnt = 0;
#pragma unroll
    for (int j = 0; j < 24; ++j)
        if (v[j] > P) { sum += __uint_as_float(v[j]); cnt++; }
#pragma unroll
    for (int off = 32; off; off >>= 1) {
        sum += __shfl_xor(sum, off);
        cnt += __shfl_xor(cnt, off);
    }
    __shared__ float fr[16];
    __shared__ unsigned ur[16];
    if (lane == 0) { fr[wid] = sum; ur[wid] = cnt; }
    __syncthreads();
    if (tid == 0) {
        float ts = 0.0f;
        unsigned tc = 0;
        for (int i = 0; i < 16; ++i) { ts += fr[i]; tc += ur[i]; }
        const float tsum = ts + (float)(k - (int)tc) * __uint_as_float(P);
        atomicAdd(&acc[3 + arr], tsum);
    }
}

// K4: final scalars.
__global__ void k_final(const float* __restrict__ acc,
                        const int* __restrict__ num_pos,
                        const int* __restrict__ n1_acc,
                        float* __restrict__ out) {
    if (threadIdx.x == 0 && blockIdx.x == 0) {
        int N = 0;
        for (int b = 0; b < BB; b++) N += num_pos[b];
        const float fN = (float)(N > 1 ? N : 1);
        const int n1 = *n1_acc;
        const float fN1 = (float)(n1 > 1 ? n1 : 1);
        out[0] = acc[0] / fN;
        out[1] = (acc[2] + acc[4]) / fN;
        out[2] = 0.4f * (acc[1] + acc[3]) / fN1;
    }
}

extern "C" void kernel_launch(void* const* d_in, const int* in_sizes, int n_in,
                              void* d_out, int out_size, void* d_ws, size_t ws_size,
                              hipStream_t stream) {
    const float* loc_data  = (const float*)d_in[0];
    const float* conf_data = (const float*)d_in[1];
    const float* obj_data  = (const float*)d_in[2];
    const float* priors    = (const float*)d_in[3];
    const float* truths    = (const float*)d_in[4];
    const int*   labels    = (const int*)d_in[5];
    float* out = (float*)d_out;

    // Workspace layout (4-byte units):
    // [0, BP)            codes (int)
    // [BP, 3BP)          mining: [0]=obj, [1]=c
    // [3BP, 3BP+1024)    best_prior: 512 ull (zeroed)
    // [3BP+1024, ...)    num_pos (32 int), acc (8 f), n1 (int)  (zeroed)
    float* ws_f = (float*)d_ws;
    int*   codes = (int*)ws_f;
    float* mining = ws_f + (size_t)BP;
    ull*   best_prior = (ull*)(ws_f + 3 * (size_t)BP);
    int*   num_pos = (int*)(ws_f + 3 * (size_t)BP + 1024);
    float* acc = ws_f + 3 * (size_t)BP + 1024 + 32;
    int*   n1_acc = (int*)(ws_f + 3 * (size_t)BP + 1024 + 48);

    hipMemsetAsync((void*)best_prior, 0, 8192, stream);

    dim3 mg((PP + CHUNK - 1) / CHUNK, BB);
    k_match_a<<<mg, 256, 0, stream>>>(priors, truths, labels, codes, best_prior);
    k_match_b<<<1, 32, 0, stream>>>(best_prior, labels, codes);

    k_ce<<<1024, 256, 0, stream>>>(conf_data, obj_data, loc_data, priors,
                                   truths, codes,
                                   mining /*obj*/, mining + BP /*c*/,
                                   num_pos, acc);

    k_select<<<64, 1024, 0, stream>>>(mining, num_pos, acc, n1_acc);

    k_final<<<1, 64, 0, stream>>>(acc, num_pos, n1_acc, out);
}